// Round 5
// baseline (3065.217 us; speedup 1.0000x reference)
//
#include <hip/hip_runtime.h>
#include <hip/hip_bf16.h>

// FlowAttention: B=4 S=4096 D=1024 H=16 dk=dv=64. Inputs/outputs fp32 (confirmed R4).
// Round-5: ws_size-overflow theory — total d_ws use now ~13.6MB; Q/K/ctx live in
// d_out (64MB) as bf16 scratch. Phase order proven race/liveness-safe:
//   P1: Q->dout[0,32), K->dout[32,64)   (weights transposed into 2MB slot, serial)
//   P2 per b: V_b->ws; middle stats; ctx_b overwrites dead K_b slice
//   P3 per b: O_b = ctx_b@Wfc -> ws slot (V dead); LN -> dout fp32 rows of b
//     (ln_b only clobbers Q (all dead) and ctx_{b'<b} (consumed) regions)
#define S_LEN 4096
#define DMODEL 1024
#define NHEAD 16
#define NROWS 16384      // B*S
#define BROWS 4096       // rows per batch

typedef __bf16 bf16x8 __attribute__((ext_vector_type(8)));
typedef float  f32x4  __attribute__((ext_vector_type(4)));

__device__ __forceinline__ float b2f(ushort u) {
    union { uint i; float f; } c; c.i = ((uint)u) << 16; return c.f;
}
__device__ __forceinline__ ushort f2b(float f) {
    union { uint i; float f; } c; c.f = f;
    uint r = c.i + 0x7FFF + ((c.i >> 16) & 1);   // round-to-nearest-even
    return (ushort)(r >> 16);
}
__device__ __forceinline__ float sigmoidf_(float x) {
    return 1.f / (1.f + __expf(-x));
}

// ---------------- transpose 1024x1024: out[n][k] = bf16(in[k][n]), in fp32 ------
__global__ void transpose_k(const float* __restrict__ in, ushort* __restrict__ out) {
    __shared__ ushort tile[32][33];
    int x = blockIdx.x * 32 + threadIdx.x;
    int y0 = blockIdx.y * 32;
    for (int i = threadIdx.y; i < 32; i += 8)
        tile[i][threadIdx.x] = f2b(in[(size_t)(y0 + i) * DMODEL + x]);
    __syncthreads();
    int xo = blockIdx.y * 32 + threadIdx.x;
    int yo0 = blockIdx.x * 32;
    for (int i = threadIdx.y; i < 32; i += 8)
        out[(size_t)(yo0 + i) * DMODEL + xo] = tile[threadIdx.x][i];
}

// ---------------- MFMA GEMM: C[M,1024] = act(A[M,1024] @ Bt^T), AF32 = A dtype --
// Block = 64x64 tile, 4 waves 2x2, each wave 32x32 via 2x2 mfma 16x16x32 bf16.
template<int AF32>
__global__ __launch_bounds__(256) void gemm_bt(const void* __restrict__ A, size_t aoff,
                                               const ushort* __restrict__ Bt,
                                               ushort* __restrict__ C, int act) {
    int n0 = blockIdx.x * 64;
    int m0 = blockIdx.y * 64;
    int lane = threadIdx.x & 63, wave = threadIdx.x >> 6;
    int wm = (wave >> 1) * 32, wn = (wave & 1) * 32;
    int fr = lane & 15;            // frag row (A) / col (B)
    int kq = (lane >> 4) * 8;      // k offset within 32-step
    size_t a0i = aoff + (size_t)(m0 + wm + fr) * DMODEL + kq;
    size_t a1i = a0i + 16 * DMODEL;
    const ushort* b0p = Bt + (size_t)(n0 + wn + fr) * DMODEL + kq;
    const ushort* b1p = b0p + 16 * DMODEL;
    f32x4 acc[2][2];
    #pragma unroll
    for (int i = 0; i < 2; ++i)
        #pragma unroll
        for (int j = 0; j < 2; ++j) acc[i][j] = (f32x4){0.f, 0.f, 0.f, 0.f};
    for (int k0 = 0; k0 < DMODEL; k0 += 32) {
        bf16x8 a0, a1;
        if (AF32) {
            const float* Af = (const float*)A;
            float4 q0 = *(const float4*)(Af + a0i + k0);
            float4 q1 = *(const float4*)(Af + a0i + k0 + 4);
            float4 q2 = *(const float4*)(Af + a1i + k0);
            float4 q3 = *(const float4*)(Af + a1i + k0 + 4);
            union { ushort u[8]; bf16x8 v; } c0, c1;
            c0.u[0]=f2b(q0.x); c0.u[1]=f2b(q0.y); c0.u[2]=f2b(q0.z); c0.u[3]=f2b(q0.w);
            c0.u[4]=f2b(q1.x); c0.u[5]=f2b(q1.y); c0.u[6]=f2b(q1.z); c0.u[7]=f2b(q1.w);
            c1.u[0]=f2b(q2.x); c1.u[1]=f2b(q2.y); c1.u[2]=f2b(q2.z); c1.u[3]=f2b(q2.w);
            c1.u[4]=f2b(q3.x); c1.u[5]=f2b(q3.y); c1.u[6]=f2b(q3.z); c1.u[7]=f2b(q3.w);
            a0 = c0.v; a1 = c1.v;
        } else {
            const ushort* Ab = (const ushort*)A;
            a0 = *(const bf16x8*)(Ab + a0i + k0);
            a1 = *(const bf16x8*)(Ab + a1i + k0);
        }
        bf16x8 b0 = *(const bf16x8*)(b0p + k0);
        bf16x8 b1 = *(const bf16x8*)(b1p + k0);
        acc[0][0] = __builtin_amdgcn_mfma_f32_16x16x32_bf16(a0, b0, acc[0][0], 0, 0, 0);
        acc[0][1] = __builtin_amdgcn_mfma_f32_16x16x32_bf16(a0, b1, acc[0][1], 0, 0, 0);
        acc[1][0] = __builtin_amdgcn_mfma_f32_16x16x32_bf16(a1, b0, acc[1][0], 0, 0, 0);
        acc[1][1] = __builtin_amdgcn_mfma_f32_16x16x32_bf16(a1, b1, acc[1][1], 0, 0, 0);
    }
    int rbase = (lane >> 4) * 4;
    int cix = lane & 15;
    #pragma unroll
    for (int i = 0; i < 2; ++i)
        #pragma unroll
        for (int j = 0; j < 2; ++j) {
            int col = n0 + wn + j * 16 + cix;
            #pragma unroll
            for (int r = 0; r < 4; ++r) {
                int row = m0 + wm + i * 16 + rbase + r;
                float v = acc[i][j][r];
                if (act) v = sigmoidf_(v);
                C[(size_t)row * DMODEL + col] = f2b(v);
            }
        }
}

// ---- column sums over S per head (optionally weighted per-s), one batch slice --
__global__ void colsum_k(const ushort* __restrict__ Q, const ushort* __restrict__ K,
                         const float* __restrict__ wq, const float* __restrict__ wk,
                         float* __restrict__ qout, float* __restrict__ kout) {
    int h = blockIdx.x;
    int d = threadIdx.x & 63, sp = threadIdx.x >> 6;
    const ushort* qp = Q + h * 64 + d;
    const ushort* kp = K + h * 64 + d;
    int s0 = blockIdx.y * (S_LEN / 8);
    float aq = 0.f, ak = 0.f;
    for (int s = s0 + sp; s < s0 + S_LEN / 8; s += 4) {
        float fq = b2f(qp[(size_t)s * DMODEL]);
        float fk = b2f(kp[(size_t)s * DMODEL]);
        if (wq) { fq *= wq[(size_t)h * S_LEN + s]; fk *= wk[(size_t)h * S_LEN + s]; }
        aq += fq; ak += fk;
    }
    __shared__ float rq[256], rk[256];
    rq[threadIdx.x] = aq; rk[threadIdx.x] = ak;
    __syncthreads();
    if (sp == 0) {
        aq = rq[d] + rq[64 + d] + rq[128 + d] + rq[192 + d];
        ak = rk[d] + rk[64 + d] + rk[128 + d] + rk[192 + d];
        atomicAdd(&qout[h * 64 + d], aq);
        atomicAdd(&kout[h * 64 + d], ak);
    }
}

// ---- per-s dots with a per-head 64-vector, one batch slice ----
__global__ void dots_k(const ushort* __restrict__ Q, const ushort* __restrict__ K,
                       const float* __restrict__ vq, const float* __restrict__ vk,
                       float* __restrict__ outq, float* __restrict__ outk, int invert) {
    int h = blockIdx.x;
    int lane = threadIdx.x & 63, wv = threadIdx.x >> 6;
    const ushort* qp = Q + h * 64 + lane;
    const ushort* kp = K + h * 64 + lane;
    float vql = vq[h * 64 + lane];
    float vkl = vk[h * 64 + lane];
    int s0 = blockIdx.y * 128 + wv * 32;
    for (int i = 0; i < 32; ++i) {
        int s = s0 + i;
        float dq = b2f(qp[(size_t)s * DMODEL]) * vql;
        float dk = b2f(kp[(size_t)s * DMODEL]) * vkl;
        #pragma unroll
        for (int off = 32; off; off >>= 1) {
            dq += __shfl_xor(dq, off);
            dk += __shfl_xor(dk, off);
        }
        if (lane == 0) {
            outq[(size_t)h * S_LEN + s] = invert ? 1.f / dq : dq;
            outk[(size_t)h * S_LEN + s] = invert ? 1.f / dk : dk;
        }
    }
}

// ---- softmax over S per head ----
__global__ void softmax_k(const float* __restrict__ x, float* __restrict__ w) {
    int h = blockIdx.x;
    const float* xp = x + (size_t)h * S_LEN;
    float loc[16];
    float mx = -1e30f;
    #pragma unroll
    for (int i = 0; i < 16; ++i) { loc[i] = xp[threadIdx.x + i * 256]; mx = fmaxf(mx, loc[i]); }
    __shared__ float red[256];
    red[threadIdx.x] = mx; __syncthreads();
    for (int st = 128; st; st >>= 1) {
        if (threadIdx.x < st) red[threadIdx.x] = fmaxf(red[threadIdx.x], red[threadIdx.x + st]);
        __syncthreads();
    }
    mx = red[0]; __syncthreads();
    float sm = 0.f;
    #pragma unroll
    for (int i = 0; i < 16; ++i) { loc[i] = __expf(loc[i] - mx); sm += loc[i]; }
    red[threadIdx.x] = sm; __syncthreads();
    for (int st = 128; st; st >>= 1) {
        if (threadIdx.x < st) red[threadIdx.x] += red[threadIdx.x + st];
        __syncthreads();
    }
    float inv = 1.f / red[0];
    #pragma unroll
    for (int i = 0; i < 16; ++i)
        w[(size_t)h * S_LEN + threadIdx.x + i * 256] = loc[i] * inv;
}

// ---- kv[h,k,v] = sum_s K[s,k]*V[s,v]*w[h,s], one batch slice (split-S atomics) --
__global__ void kv_k(const ushort* __restrict__ K, const ushort* __restrict__ V,
                     const float* __restrict__ w, float* __restrict__ kv) {
    int h = blockIdx.x;
    const ushort* kp = K + h * 64;
    const ushort* vp = V + h * 64;
    int tid = threadIdx.x;
    int kk = tid >> 2;
    int v0 = (tid & 3) * 16;
    __shared__ ushort Kt[64][64];
    __shared__ ushort Vt[64][64];
    __shared__ float wt[64];
    float acc[16];
    #pragma unroll
    for (int j = 0; j < 16; ++j) acc[j] = 0.f;
    int sBase = blockIdx.y * (S_LEN / 8);
    for (int t0 = 0; t0 < S_LEN / 8; t0 += 64) {
        __syncthreads();
        #pragma unroll
        for (int i = 0; i < 16; ++i) {
            int idx = tid + i * 256;
            int sl = idx >> 6, d = idx & 63;
            size_t g = (size_t)(sBase + t0 + sl) * DMODEL + d;
            Kt[sl][d] = kp[g];
            Vt[sl][d] = vp[g];
        }
        if (tid < 64) wt[tid] = w[(size_t)h * S_LEN + sBase + t0 + tid];
        __syncthreads();
        for (int sl = 0; sl < 64; ++sl) {
            float kwv = b2f(Kt[sl][kk]) * wt[sl];
            #pragma unroll
            for (int j = 0; j < 16; ++j)
                acc[j] += kwv * b2f(Vt[sl][v0 + j]);
        }
    }
    float* kvp = kv + (size_t)h * 4096;
    #pragma unroll
    for (int j = 0; j < 16; ++j)
        atomicAdd(&kvp[kk * 64 + v0 + j], acc[j]);
}

// ---- ctx[s,h*64+v] = sig(csink[h,s])*si[h,s]*sum_k Q[s,h*64+k]*kv[h,k,v] ----
// ctx may alias K's memory (K dead): write-only, launched after kv_k.
__global__ void ctx_k(const ushort* __restrict__ Q, const float* __restrict__ kv,
                      const float* __restrict__ si, const float* __restrict__ csink,
                      ushort* __restrict__ ctx) {
    int h = blockIdx.x;
    int lane = threadIdx.x & 63, wv = threadIdx.x >> 6;
    __shared__ float kvf[64][64];
    #pragma unroll
    for (int i = 0; i < 16; ++i) {
        int idx = threadIdx.x + i * 256;
        kvf[idx >> 6][idx & 63] = kv[(size_t)h * 4096 + idx];
    }
    __syncthreads();
    const ushort* qp = Q + h * 64 + lane;
    ushort* cp = ctx + h * 64 + lane;
    int s0 = blockIdx.y * 256 + wv * 64;
    for (int i = 0; i < 64; ++i) {
        int s = s0 + i;
        float qv = b2f(qp[(size_t)s * DMODEL]);
        float scale = si[(size_t)h * S_LEN + s] * sigmoidf_(csink[(size_t)h * S_LEN + s]);
        float acc = 0.f;
        #pragma unroll
        for (int k = 0; k < 64; ++k)
            acc += __shfl(qv, k) * kvf[k][lane];
        cp[(size_t)s * DMODEL] = f2b(acc * scale);
    }
}

// ---- LayerNorm(y_bf16 + residual_f32) * gamma + beta -> fp32 out (per-row) ----
__global__ void ln_k(const ushort* __restrict__ y, const float* __restrict__ res,
                     const float* __restrict__ gamma, const float* __restrict__ beta,
                     float* __restrict__ out) {
    size_t row = blockIdx.x;
    const ushort* yp = y + row * DMODEL;
    const float* rp = res + row * DMODEL;
    float x[4];
    float s = 0.f, s2 = 0.f;
    #pragma unroll
    for (int i = 0; i < 4; ++i) {
        int d = threadIdx.x + i * 256;
        x[i] = b2f(yp[d]) + rp[d];
        s += x[i]; s2 += x[i] * x[i];
    }
    __shared__ float r1[256], r2[256];
    r1[threadIdx.x] = s; r2[threadIdx.x] = s2;
    __syncthreads();
    for (int st = 128; st; st >>= 1) {
        if (threadIdx.x < st) { r1[threadIdx.x] += r1[threadIdx.x + st]; r2[threadIdx.x] += r2[threadIdx.x + st]; }
        __syncthreads();
    }
    float mean = r1[0] * (1.f / DMODEL);
    float var = r2[0] * (1.f / DMODEL) - mean * mean;
    float rstd = rsqrtf(var + 1e-5f);
    #pragma unroll
    for (int i = 0; i < 4; ++i) {
        int d = threadIdx.x + i * 256;
        out[row * DMODEL + d] = (x[i] - mean) * rstd * gamma[d] + beta[d];
    }
}

extern "C" void kernel_launch(void* const* d_in, const int* in_sizes, int n_in,
                              void* d_out, int out_size, void* d_ws, size_t ws_size,
                              hipStream_t stream) {
    const float* inQ  = (const float*)d_in[0];
    const float* inK  = (const float*)d_in[1];
    const float* inV  = (const float*)d_in[2];
    const float* WQ   = (const float*)d_in[3];
    const float* WK   = (const float*)d_in[4];
    const float* WV   = (const float*)d_in[5];
    const float* WF   = (const float*)d_in[6];
    const float* gamma= (const float*)d_in[7];
    const float* beta = (const float*)d_in[8];
    float* outf = (float*)d_out;

    // d_out scratch: bf16 Q at [0,32MB), bf16 K/ctx at [32,64MB)
    ushort* Qb  = (ushort*)d_out;
    ushort* KCb = (ushort*)d_out + (size_t)NROWS * DMODEL;  // element offset 16M

    // d_ws: ~13.6MB total
    const size_t MB = 1024ull * 1024ull;
    char* w = (char*)d_ws;
    ushort* Vb  = (ushort*)w;                 // [4096][1024] bf16, 8MB; later O_b slot
    ushort* Wt0 = (ushort*)(w + 8 * MB);      // 2MB transposed-weight slot (WQ/WK/WV)
    ushort* Wt1 = (ushort*)(w + 10 * MB);     // 2MB (WF)
    float* si   = (float*)(w + 12 * MB);      // [16][4096] fp32, 256KB each
    float* so   = si  + NHEAD * S_LEN;
    float* csk  = so  + NHEAD * S_LEN;
    float* css  = csk + NHEAD * S_LEN;
    float* smw  = css + NHEAD * S_LEN;
    float* Qsum = smw + NHEAD * S_LEN;        // [16][64] x4 = 16KB (atomic, zeroed/batch)
    float* Ksum = Qsum + NHEAD * 64;
    float* QsI  = Ksum + NHEAD * 64;
    float* KsO  = QsI  + NHEAD * 64;
    float* kvb  = KsO  + NHEAD * 64;          // [16][64][64] fp32, 256KB (atomic)
    size_t zeroBytes = (4 * NHEAD * 64 + NHEAD * 4096) * sizeof(float); // 272KB

    dim3 tb(32, 8);
    dim3 tg(32, 32);
    dim3 ggFull(DMODEL / 64, NROWS / 64);     // (16, 256)
    dim3 ggBat(DMODEL / 64, BROWS / 64);      // (16, 64)

    // Phase 1: Q and K projections (full batch) into d_out
    transpose_k<<<tg, tb, 0, stream>>>(WQ, Wt0);
    gemm_bt<1><<<ggFull, 256, 0, stream>>>(inQ, 0, Wt0, Qb, 1);
    transpose_k<<<tg, tb, 0, stream>>>(WK, Wt0);
    gemm_bt<1><<<ggFull, 256, 0, stream>>>(inK, 0, Wt0, KCb, 1);
    transpose_k<<<tg, tb, 0, stream>>>(WV, Wt0);
    transpose_k<<<tg, tb, 0, stream>>>(WF, Wt1);

    // Phase 2: per-batch attention middle; ctx_b overwrites dead K_b slice
    for (int b = 0; b < 4; ++b) {
        size_t rowOff = (size_t)b * BROWS * DMODEL;
        const ushort* Qs = Qb + rowOff;
        ushort* Ks = KCb + rowOff;
        hipMemsetAsync(Qsum, 0, zeroBytes, stream);
        gemm_bt<1><<<ggBat, 256, 0, stream>>>(inV, rowOff, Wt0, Vb, 0);
        colsum_k<<<dim3(NHEAD, 8), 256, 0, stream>>>(Qs, Ks, nullptr, nullptr, Qsum, Ksum);
        dots_k<<<dim3(NHEAD, 32), 256, 0, stream>>>(Qs, Ks, Ksum, Qsum, si, so, 1);
        colsum_k<<<dim3(NHEAD, 8), 256, 0, stream>>>(Qs, Ks, si, so, QsI, KsO);
        dots_k<<<dim3(NHEAD, 32), 256, 0, stream>>>(Qs, Ks, KsO, QsI, csk, css, 0);
        softmax_k<<<NHEAD, 256, 0, stream>>>(css, smw);
        kv_k<<<dim3(NHEAD, 8), 256, 0, stream>>>(Ks, Vb, smw, kvb);
        ctx_k<<<dim3(NHEAD, 16), 256, 0, stream>>>(Qs, kvb, si, csk, Ks);
    }

    // Phase 3: per-batch output projection + LayerNorm (fp32 out)
    // ln_b writes d_out fp32 rows [b*4096, (b+1)*4096) — only clobbers dead Q
    // region (b=0,1) and already-consumed ctx regions (b=2,3).
    for (int b = 0; b < 4; ++b) {
        size_t rowOff = (size_t)b * BROWS * DMODEL;
        gemm_bt<0><<<ggBat, 256, 0, stream>>>(KCb + rowOff, 0, Wt1, Vb, 0);
        ln_k<<<BROWS, 256, 0, stream>>>(Vb, inQ + rowOff, gamma, beta, outf + rowOff);
    }
}